// Round 12
// baseline (78.195 us; speedup 1.0000x reference)
//
#include <hip/hip_runtime.h>
#include <hip/hip_bf16.h>

typedef __bf16 bf16_t;
typedef __bf16 bf16x4 __attribute__((ext_vector_type(4)));
typedef __bf16 bf16x8 __attribute__((ext_vector_type(8)));
typedef float f32x4 __attribute__((ext_vector_type(4)));

#define S_LEN 2048
#define DMODEL 1024
#define NHEADS 16
#define HDIM 64
#define BROWS 4096   // B * S
#define QKVN 3072    // fused QKV output width

__device__ __forceinline__ void async16(const void* g, void* l) {
  __builtin_amdgcn_global_load_lds(
      (const __attribute__((address_space(1))) void*)g,
      (__attribute__((address_space(3))) void*)l, 16, 0, 0);
}

// ------------- fused f32 -> bf16 conversion (x, Wq, Wk, Wv, Wo) -------------
__global__ __launch_bounds__(256) void cvt_all_kernel(
    const float* __restrict__ x, const float* __restrict__ Wq,
    const float* __restrict__ Wk, const float* __restrict__ Wv,
    const float* __restrict__ Wo, bf16_t* __restrict__ dst) {
  const int i = blockIdx.x * 256 + threadIdx.x;  // float4 index
  constexpr int XN4 = (BROWS * DMODEL) / 4;      // 1048576
  constexpr int WN4 = (DMODEL * DMODEL) / 4;     // 262144
  const float* src;
  size_t off;
  if (i < XN4) {
    src = x;
    off = (size_t)i;
  } else {
    const int wi = i - XN4;
    const int w = wi >> 18;
    off = (size_t)(wi & (WN4 - 1));
    src = (w == 0) ? Wq : (w == 1) ? Wk : (w == 2) ? Wv : Wo;
  }
  const float4 v = *(const float4*)(src + off * 4);
  bf16x4 o;
  o[0] = (bf16_t)v.x;
  o[1] = (bf16_t)v.y;
  o[2] = (bf16_t)v.z;
  o[3] = (bf16_t)v.w;
  *(bf16x4*)(dst + (size_t)i * 4) = o;
}

// ================ 256x192 8-phase GEMM (QKV, full-chip grid) ================
// Round-12: race-free gate discipline.  vmcnt is PER-WAVE but tiles are
// staged cooperatively, so the only safe order is VMC -> BARRIER -> reads
// (barrier-release certifies all waves' loads landed).  P4/P8 end with
// VMC+BARR; all reads of the newly-gated tile happen at the TOP of the next
// phase.  aS1/B read-ahead retained (read at P1/P5, consumed at P3/P7).
#define BARR __builtin_amdgcn_s_barrier()
#define SB0 __builtin_amdgcn_sched_barrier(0)
#define VMC3 asm volatile("s_waitcnt vmcnt(3)" ::: "memory")
#define VMC0 asm volatile("s_waitcnt vmcnt(0)" ::: "memory")

__global__ __launch_bounds__(512, 2) void gemm_qkv256_kernel(
    const bf16_t* __restrict__ A, const bf16_t* __restrict__ W,
    const float* __restrict__ bq, const float* __restrict__ bk,
    const float* __restrict__ bv, bf16_t* __restrict__ C) {
  constexpr int Kd = 1024;
  __shared__ char lds[114688];  // A: 2*256*128B = 64KB, B: 2*192*128B = 48KB
  char* ldsA = lds;
  char* ldsB = lds + 65536;

  const int m0 = blockIdx.x * 256;
  const int n0 = blockIdx.y * 192;

  const int tid = threadIdx.x;
  const int lane = tid & 63;
  const int wid = tid >> 6;
  const int wr = wid >> 2;  // 0..1 (128 rows)
  const int wc = wid & 3;   // 0..3 (48 cols)
  const int fr = lane & 15;
  const int l16 = lane >> 4;

  f32x4 acc[8][3] = {};
  bf16x8 aS0[4][2], aS1[4][2], bB[3][2];

  auto stageA = [&](int buf, int h, int kt) {
#pragma unroll
    for (int l = 0; l < 2; ++l) {
      const int idx = l * 512 + tid;
      const int r = idx >> 3;  // 0..127
      const int slot = idx & 7;
      async16((const char*)(A + (size_t)(m0 + h * 128 + r) * Kd + kt * 64 +
                            ((slot ^ (r & 7)) << 3)),
              ldsA + buf * 32768 + h * 16384 + r * 128 + slot * 16);
    }
  };
  auto stageB = [&](int buf, int th, int kt) {
    const int r = tid >> 3;  // 0..63
    const int slot = tid & 7;
    async16((const char*)(W + (size_t)(n0 + th * 64 + r) * Kd + kt * 64 +
                          ((slot ^ (r & 7)) << 3)),
            ldsB + buf * 24576 + th * 8192 + r * 128 + slot * 16);
  };

  auto rdA = [&](int buf, int row, int ks) -> bf16x8 {
    return *(const bf16x8*)(ldsA + buf * 32768 + row * 128 +
                            ((((ks << 2) + l16) ^ (row & 7)) << 4));
  };
  auto rdB = [&](int buf, int row, int ks) -> bf16x8 {
    return *(const bf16x8*)(ldsB + buf * 24576 + row * 128 +
                            ((((ks << 2) + l16) ^ (row & 7)) << 4));
  };

#define RDA_TO(AS, MH, BUF)                                              \
  _Pragma("unroll") for (int m_ = 0; m_ < 4; ++m_)                       \
      _Pragma("unroll") for (int ks_ = 0; ks_ < 2; ++ks_) AS[m_][ks_] =  \
          rdA(BUF, wr * 128 + (MH)*64 + m_ * 16 + fr, ks_);
#define RDB(NF0, NC, BUF)                                                \
  _Pragma("unroll") for (int n_ = 0; n_ < (NC); ++n_)                    \
      _Pragma("unroll") for (int ks_ = 0; ks_ < 2; ++ks_)                \
          bB[(NF0) + n_][ks_] =                                          \
              rdB(BUF, wc * 48 + ((NF0) + n_) * 16 + fr, ks_);
#define MMAQ(AS, MH, NF0, NC)                                                 \
  _Pragma("unroll") for (int m_ = 0; m_ < 4; ++m_)                            \
      _Pragma("unroll") for (int n_ = 0; n_ < (NC); ++n_) {                   \
    acc[(MH)*4 + m_][(NF0) + n_] = __builtin_amdgcn_mfma_f32_16x16x32_bf16(   \
        AS[m_][0], bB[(NF0) + n_][0], acc[(MH)*4 + m_][(NF0) + n_], 0, 0, 0); \
    acc[(MH)*4 + m_][(NF0) + n_] = __builtin_amdgcn_mfma_f32_16x16x32_bf16(   \
        AS[m_][1], bB[(NF0) + n_][1], acc[(MH)*4 + m_][(NF0) + n_], 0, 0, 0); \
  }

  // prologue: tile0 (A 4 + B 3) -> buf0, B(t1) 3 -> buf1; gate tile0.
  stageA(0, 0, 0);
  stageA(0, 1, 0);
  stageB(0, 0, 0);
  stageB(0, 1, 0);
  stageB(0, 2, 0);
  stageB(1, 0, 1);
  stageB(1, 1, 1);
  stageB(1, 2, 1);
  VMC3;  // 10 outstanding -> retire oldest 7 = all of tile0 (this wave)
  BARR;  // ...and barrier-release certifies ALL waves' tile0 loads

#pragma unroll 1
  for (int i = 0; i < 8; ++i) {
    const int t0 = 2 * i, t1 = 2 * i + 1;
    const bool st = (i < 7);
    // P1: read aS0+B01+aS1 of t0 (buf0, gated by prev VMC+BARR);
    //     stage A-h0(t1)->buf1
    RDA_TO(aS0, 0, 0);
    RDB(0, 2, 0);
    RDA_TO(aS1, 1, 0);
    stageA(1, 0, t1);
    SB0;
    BARR;
    __builtin_amdgcn_s_setprio(1);
    MMAQ(aS0, 0, 0, 2);
    __builtin_amdgcn_s_setprio(0);
    BARR;
    // P2: read B2 (buf0); stage A-h1(t1)->buf1
    RDB(2, 1, 0);
    stageA(1, 1, t1);
    SB0;
    BARR;
    __builtin_amdgcn_s_setprio(1);
    MMAQ(aS0, 0, 2, 1);
    __builtin_amdgcn_s_setprio(0);
    BARR;
    // P3: MFMA on aS1 (read-ahead from P1); stage B-third0(t0+2)->buf0
    if (st) stageB(0, 0, t0 + 2);
    SB0;
    BARR;
    __builtin_amdgcn_s_setprio(1);
    MMAQ(aS1, 1, 0, 2);
    __builtin_amdgcn_s_setprio(0);
    BARR;
    // P4: stage B-third1,2(t0+2); VMC gate for tile t1 BEFORE the barrier
    if (st) {
      stageB(0, 1, t0 + 2);
      stageB(0, 2, t0 + 2);
    }
    SB0;
    __builtin_amdgcn_s_setprio(1);
    MMAQ(aS1, 1, 2, 1);
    __builtin_amdgcn_s_setprio(0);
    SB0;
    if (st) {
      VMC3;  // retires prevP7+prevP8+P1+P2 stages = all 7 of tile t1
    } else {
      VMC0;  // last iter: drain (tile 15 fully resident)
    }
    BARR;    // certifies tile t1 across ALL waves
    // P5: read aS0+B01+aS1 of t1 (buf1); stage A-h0(t0+2)->buf0
    RDA_TO(aS0, 0, 1);
    RDB(0, 2, 1);
    RDA_TO(aS1, 1, 1);
    if (st) stageA(0, 0, t0 + 2);
    SB0;
    BARR;
    __builtin_amdgcn_s_setprio(1);
    MMAQ(aS0, 0, 0, 2);
    __builtin_amdgcn_s_setprio(0);
    BARR;
    // P6: read B2 (buf1); stage A-h1(t0+2)->buf0
    RDB(2, 1, 1);
    if (st) stageA(0, 1, t0 + 2);
    SB0;
    BARR;
    __builtin_amdgcn_s_setprio(1);
    MMAQ(aS0, 0, 2, 1);
    __builtin_amdgcn_s_setprio(0);
    BARR;
    // P7: MFMA on aS1 (read-ahead from P5); stage B-third0(t1+2)->buf1
    if (st) stageB(1, 0, t1 + 2);
    SB0;
    BARR;
    __builtin_amdgcn_s_setprio(1);
    MMAQ(aS1, 1, 0, 2);
    __builtin_amdgcn_s_setprio(0);
    BARR;
    // P8: stage B-third1,2(t1+2); VMC gate for tile t0+2 BEFORE the barrier
    if (st) {
      stageB(1, 1, t1 + 2);
      stageB(1, 2, t1 + 2);
    }
    SB0;
    __builtin_amdgcn_s_setprio(1);
    MMAQ(aS1, 1, 2, 1);
    __builtin_amdgcn_s_setprio(0);
    SB0;
    if (st) VMC3;  // retires P3..P6 stages = all 7 of tile t0+2
    BARR;
  }
#undef RDA_TO
#undef RDB
#undef MMAQ

  // epilogue: C/D layout col = lane&15, row = (lane>>4)*4 + reg  [m89]
  const int cr = l16 * 4;
#pragma unroll
  for (int nf = 0; nf < 3; ++nf) {
    const int col = n0 + wc * 48 + nf * 16 + fr;  // 0..3071
    const int mat = col >> 10;
    const float* bp = (mat == 0) ? bq : (mat == 1) ? bk : bv;
    const float bval = bp[col & 1023];
#pragma unroll
    for (int mf = 0; mf < 8; ++mf) {
      const int row = m0 + wr * 128 + mf * 16 + cr;
#pragma unroll
      for (int r = 0; r < 4; ++r)
        C[(size_t)(row + r) * QKVN + col] = (bf16_t)(acc[mf][nf][r] + bval);
    }
  }
}

// ============== 128x128 GEMM, 8 waves (O-projection, 2 waves/SIMD) ==========
__global__ __launch_bounds__(512) void gemm_o_kernel(
    const bf16_t* __restrict__ Adat, const bf16_t* __restrict__ W,
    const float* __restrict__ bias, float* __restrict__ out) {
  constexpr int Kd = 1024, Nd = 1024, BK = 32, NT = Kd / BK;
  __shared__ bf16_t ldsA[2][128 * BK];
  __shared__ bf16_t ldsB[2][128 * BK];

  const int m0 = blockIdx.x * 128;
  const int n0 = blockIdx.y * 128;

  const int tid = threadIdx.x;
  const int lane = tid & 63;
  const int wid = tid >> 6;
  const int wr = wid >> 2;  // 0..1 (64 rows each)
  const int wc = wid & 3;   // 0..3 (32 cols each)
  const int fr = lane & 15;
  const int ko = (lane >> 4) * 8;

  f32x4 acc[4][2] = {};

  auto stage = [&](int buf, int t) {
    const int k0 = t * BK;
    const int row = tid >> 2;       // 0..127
    const int kb = (tid & 3) * 16;  // byte offset in 64B row
    async16((const char*)(Adat + (size_t)(m0 + row) * Kd + k0) + kb,
            (char*)ldsA[buf] + row * 64 + kb);
    async16((const char*)(W + (size_t)(n0 + row) * Kd + k0) + kb,
            (char*)ldsB[buf] + row * 64 + kb);
  };

  auto compute = [&](int buf) {
    bf16x8 af[4], bf[2];
#pragma unroll
    for (int i = 0; i < 4; ++i)
      af[i] = *(const bf16x8*)(ldsA[buf] + (wr * 64 + i * 16 + fr) * BK + ko);
#pragma unroll
    for (int j = 0; j < 2; ++j)
      bf[j] = *(const bf16x8*)(ldsB[buf] + (wc * 32 + j * 16 + fr) * BK + ko);
#pragma unroll
    for (int i = 0; i < 4; ++i)
#pragma unroll
      for (int j = 0; j < 2; ++j)
        acc[i][j] = __builtin_amdgcn_mfma_f32_16x16x32_bf16(af[i], bf[j],
                                                            acc[i][j], 0, 0, 0);
  };

  stage(0, 0);
  __syncthreads();
#pragma unroll 1
  for (int t = 0; t < NT; ++t) {
    if (t + 1 < NT) stage((t + 1) & 1, t + 1);
    compute(t & 1);
    __syncthreads();
  }

  const int cr = (lane >> 4) * 4;
#pragma unroll
  for (int j = 0; j < 2; ++j) {
    const int col = n0 + wc * 32 + j * 16 + fr;
    const float bval = bias[col];
#pragma unroll
    for (int i = 0; i < 4; ++i) {
#pragma unroll
      for (int r = 0; r < 4; ++r) {
        const int row = m0 + wr * 64 + i * 16 + cr + r;
        out[(size_t)row * Nd + col] = acc[i][j][r] + bval;
      }
    }
  }
}

// ---------------- local attention (thread-per-query, fused QKV in) ---------
#define CHUNK 256
#define TROWS 260

__global__ __launch_bounds__(256) void attn_kernel(
    const bf16_t* __restrict__ QKV, bf16_t* __restrict__ ctx) {
  __shared__ bf16_t ldsK[TROWS * HDIM];
  __shared__ bf16_t ldsV[TROWS * HDIM];

  const int tid = threadIdx.x;
  const int blk = blockIdx.x;
  const int chunk = blk & 7;
  const int bh = blk >> 3;
  const int h = bh & (NHEADS - 1);
  const int b = bh >> 4;
  const int s0 = chunk * CHUNK;

  const bf16_t* Kb = QKV + (size_t)b * S_LEN * QKVN + DMODEL + h * HDIM;
  const bf16_t* Vb = QKV + (size_t)b * S_LEN * QKVN + 2 * DMODEL + h * HDIM;

#pragma unroll
  for (int j = 0; j < 9; ++j) {
    const int i = j * 256 + tid;
    if (i < TROWS * 8) {
      const int tr = i >> 3;
      const int slot = i & 7;
      const int c = slot ^ (tr & 7);
      int gs = s0 - 2 + tr;
      gs = (gs < 0) ? 0 : (gs >= S_LEN ? S_LEN - 1 : gs);
      async16((const char*)(Kb + (size_t)gs * QKVN) + c * 16,
              (char*)ldsK + i * 16);
      async16((const char*)(Vb + (size_t)gs * QKVN) + c * 16,
              (char*)ldsV + i * 16);
    }
  }

  const int s = s0 + tid;
  const bf16_t* Qrow = QKV + ((size_t)(b * S_LEN) + s) * QKVN + h * HDIM;
  bf16x8 q8[8];
#pragma unroll
  for (int c = 0; c < 8; ++c) q8[c] = *(const bf16x8*)(Qrow + c * 8);
  float qf[64];
#pragma unroll
  for (int c = 0; c < 8; ++c)
#pragma unroll
    for (int e = 0; e < 8; ++e) qf[c * 8 + e] = (float)q8[c][e];

  __syncthreads();

  float sc[5];
#pragma unroll
  for (int jj = 0; jj < 5; ++jj) {
    const int tr = tid + jj;
    float d = 0.f;
#pragma unroll
    for (int c = 0; c < 8; ++c) {
      const bf16x8 k8 = *(const bf16x8*)(ldsK + tr * HDIM + (c ^ (tr & 7)) * 8);
#pragma unroll
      for (int e = 0; e < 8; ++e) d += qf[c * 8 + e] * (float)k8[e];
    }
    const int j = s - 2 + jj;
    sc[jj] = (j < 0 || j >= S_LEN) ? -1e30f : d * 0.125f;
  }

  float m = sc[0];
#pragma unroll
  for (int jj = 1; jj < 5; ++jj) m = fmaxf(m, sc[jj]);
  float p[5], l = 0.f;
#pragma unroll
  for (int jj = 0; jj < 5; ++jj) {
    p[jj] = __expf(sc[jj] - m);
    l += p[jj];
  }
  const float inv = 1.0f / l;
#pragma unroll
  for (int jj = 0; jj < 5; ++jj) p[jj] *= inv;

  float o[64];
#pragma unroll
  for (int e = 0; e < 64; ++e) o[e] = 0.f;
#pragma unroll
  for (int jj = 0; jj < 5; ++jj) {
    const int tr = tid + jj;
    const float pj = p[jj];
#pragma unroll
    for (int c = 0; c < 8; ++c) {
      const bf16x8 v8 = *(const bf16x8*)(ldsV + tr * HDIM + (c ^ (tr & 7)) * 8);
#pragma unroll
      for (int e = 0; e < 8; ++e) o[c * 8 + e] += pj * (float)v8[e];
    }
  }

  bf16_t* Crow = (bf16_t*)ctx + ((size_t)(b * S_LEN) + s) * DMODEL + h * HDIM;
#pragma unroll
  for (int c = 0; c < 8; ++c) {
    bf16x8 ov;
#pragma unroll
    for (int e = 0; e < 8; ++e) ov[e] = (bf16_t)o[c * 8 + e];
    *(bf16x8*)(Crow + c * 8) = ov;
  }
}

extern "C" void kernel_launch(void* const* d_in, const int* in_sizes, int n_in,
                              void* d_out, int out_size, void* d_ws,
                              size_t ws_size, hipStream_t stream) {
  const float* x = (const float*)d_in[0];
  const float* Wq = (const float*)d_in[1];
  const float* bq = (const float*)d_in[2];
  const float* Wk = (const float*)d_in[3];
  const float* bk = (const float*)d_in[4];
  const float* Wv = (const float*)d_in[5];
  const float* bv = (const float*)d_in[6];
  const float* Wo = (const float*)d_in[7];
  const float* bo = (const float*)d_in[8];
  float* out = (float*)d_out;

  const size_t mat = (size_t)BROWS * DMODEL;
  const size_t wmat = (size_t)DMODEL * DMODEL;
  bf16_t* xb = (bf16_t*)d_ws;   // [xb | Wqkv | Wob] contiguous (cvt dst)
  bf16_t* Wqkv = xb + mat;      // fused [3072][1024]
  bf16_t* Wob = Wqkv + 3 * wmat;
  bf16_t* QKV = Wob + wmat;     // fused [4096][3072]
  bf16_t* ctx = QKV + 3 * mat;

  cvt_all_kernel<<<8192, 256, 0, stream>>>(x, Wq, Wk, Wv, Wo, xb);
  gemm_qkv256_kernel<<<dim3(16, 16), 512, 0, stream>>>(xb, Wqkv, bq, bk, bv,
                                                       QKV);
  attn_kernel<<<256, 256, 0, stream>>>(QKV, ctx);
  gemm_o_kernel<<<dim3(32, 8), 512, 0, stream>>>(ctx, Wob, bo, out);
}

// Round 13
// 77.410 us; speedup vs baseline: 1.0101x; 1.0101x over previous
//
#include <hip/hip_runtime.h>
#include <hip/hip_bf16.h>

typedef __bf16 bf16_t;
typedef __bf16 bf16x4 __attribute__((ext_vector_type(4)));
typedef __bf16 bf16x8 __attribute__((ext_vector_type(8)));
typedef float f32x4 __attribute__((ext_vector_type(4)));

#define S_LEN 2048
#define DMODEL 1024
#define NHEADS 16
#define HDIM 64
#define BROWS 4096   // B * S
#define QKVN 3072    // fused QKV output width

__device__ __forceinline__ void async16(const void* g, void* l) {
  __builtin_amdgcn_global_load_lds(
      (const __attribute__((address_space(1))) void*)g,
      (__attribute__((address_space(3))) void*)l, 16, 0, 0);
}

// ------------- fused f32 -> bf16 conversion (x, Wq, Wk, Wv, Wo) -------------
__global__ __launch_bounds__(256) void cvt_all_kernel(
    const float* __restrict__ x, const float* __restrict__ Wq,
    const float* __restrict__ Wk, const float* __restrict__ Wv,
    const float* __restrict__ Wo, bf16_t* __restrict__ dst) {
  const int i = blockIdx.x * 256 + threadIdx.x;  // float4 index
  constexpr int XN4 = (BROWS * DMODEL) / 4;      // 1048576
  constexpr int WN4 = (DMODEL * DMODEL) / 4;     // 262144
  const float* src;
  size_t off;
  if (i < XN4) {
    src = x;
    off = (size_t)i;
  } else {
    const int wi = i - XN4;
    const int w = wi >> 18;
    off = (size_t)(wi & (WN4 - 1));
    src = (w == 0) ? Wq : (w == 1) ? Wk : (w == 2) ? Wv : Wo;
  }
  const float4 v = *(const float4*)(src + off * 4);
  bf16x4 o;
  o[0] = (bf16_t)v.x;
  o[1] = (bf16_t)v.y;
  o[2] = (bf16_t)v.z;
  o[3] = (bf16_t)v.w;
  *(bf16x4*)(dst + (size_t)i * 4) = o;
}

// ============ 256x192 single-phase GEMM (QKV): 2 barriers/tile ==============
// Round-13: r12 ran 8 barriers/tile (128 total); straggler-resync at ~200-400
// cyc each explains the 29us plateau.  New loop = ONE phase per K-tile:
//   READS(buf) -> LGKM0 -> BARR#1 (all waves done reading buf)
//   -> STAGE(t+2 -> buf) -> 48 MFMA -> VMC7 -> BARR#2 (certify tile t+1)
// Gate discipline kept from r12: per-wave VMC *then* barrier = cooperative
// certification; stage only after the barrier proving all reads retired.
#define BARR __builtin_amdgcn_s_barrier()
#define LGKM0 asm volatile("s_waitcnt lgkmcnt(0)" ::: "memory")
#define VMC7 asm volatile("s_waitcnt vmcnt(7)" ::: "memory")
#define VMC0 asm volatile("s_waitcnt vmcnt(0)" ::: "memory")

__global__ __launch_bounds__(512, 2) void gemm_qkv256_kernel(
    const bf16_t* __restrict__ A, const bf16_t* __restrict__ W,
    const float* __restrict__ bq, const float* __restrict__ bk,
    const float* __restrict__ bv, bf16_t* __restrict__ C) {
  constexpr int Kd = 1024;
  __shared__ char lds[114688];  // A: 2*256*128B = 64KB, B: 2*192*128B = 48KB
  char* ldsA = lds;
  char* ldsB = lds + 65536;

  const int m0 = blockIdx.x * 256;
  const int n0 = blockIdx.y * 192;

  const int tid = threadIdx.x;
  const int lane = tid & 63;
  const int wid = tid >> 6;
  const int wr = wid >> 2;  // 0..1 (128 rows)
  const int wc = wid & 3;   // 0..3 (48 cols)
  const int fr = lane & 15;
  const int l16 = lane >> 4;

  f32x4 acc[8][3] = {};
  bf16x8 aS0[4][2], aS1[4][2], bB[3][2];

  auto stageA = [&](int buf, int h, int kt) {
#pragma unroll
    for (int l = 0; l < 2; ++l) {
      const int idx = l * 512 + tid;
      const int r = idx >> 3;  // 0..127
      const int slot = idx & 7;
      async16((const char*)(A + (size_t)(m0 + h * 128 + r) * Kd + kt * 64 +
                            ((slot ^ (r & 7)) << 3)),
              ldsA + buf * 32768 + h * 16384 + r * 128 + slot * 16);
    }
  };
  auto stageB = [&](int buf, int th, int kt) {
    const int r = tid >> 3;  // 0..63
    const int slot = tid & 7;
    async16((const char*)(W + (size_t)(n0 + th * 64 + r) * Kd + kt * 64 +
                          ((slot ^ (r & 7)) << 3)),
            ldsB + buf * 24576 + th * 8192 + r * 128 + slot * 16);
  };

  auto rdA = [&](int buf, int row, int ks) -> bf16x8 {
    return *(const bf16x8*)(ldsA + buf * 32768 + row * 128 +
                            ((((ks << 2) + l16) ^ (row & 7)) << 4));
  };
  auto rdB = [&](int buf, int row, int ks) -> bf16x8 {
    return *(const bf16x8*)(ldsB + buf * 24576 + row * 128 +
                            ((((ks << 2) + l16) ^ (row & 7)) << 4));
  };

  // prologue: tile0 -> buf0 (7), tile1 -> buf1 (7); certify tile0.
  stageA(0, 0, 0);
  stageA(0, 1, 0);
  stageB(0, 0, 0);
  stageB(0, 1, 0);
  stageB(0, 2, 0);
  stageA(1, 0, 1);
  stageA(1, 1, 1);
  stageB(1, 0, 1);
  stageB(1, 1, 1);
  stageB(1, 2, 1);
  VMC7;  // 14 outstanding -> retire oldest 7 = all of tile0 (own)
  BARR;  // barrier-release certifies tile0 across all waves

#pragma unroll 1
  for (int t = 0; t < 16; ++t) {
    const int buf = t & 1;
    // --- reads: full tile t (22 x ds_read_b128), compiler-scheduled
#pragma unroll
    for (int m_ = 0; m_ < 4; ++m_)
#pragma unroll
      for (int ks_ = 0; ks_ < 2; ++ks_) {
        aS0[m_][ks_] = rdA(buf, wr * 128 + m_ * 16 + fr, ks_);
        aS1[m_][ks_] = rdA(buf, wr * 128 + 64 + m_ * 16 + fr, ks_);
      }
#pragma unroll
    for (int n_ = 0; n_ < 3; ++n_)
#pragma unroll
      for (int ks_ = 0; ks_ < 2; ++ks_)
        bB[n_][ks_] = rdB(buf, wc * 48 + n_ * 16 + fr, ks_);
    LGKM0;  // own reads retired...
    BARR;   // ...and ALL waves' reads retired -> safe to overwrite buf
    // --- stage tile t+2 into the region just vacated
    if (t + 2 < 16) {
      stageA(buf, 0, t + 2);
      stageA(buf, 1, t + 2);
      stageB(buf, 0, t + 2);
      stageB(buf, 1, t + 2);
      stageB(buf, 2, t + 2);
    }
    // --- 48 MFMA on registers (hides staging issue + VMC wait below)
    __builtin_amdgcn_s_setprio(1);
#pragma unroll
    for (int m_ = 0; m_ < 4; ++m_)
#pragma unroll
      for (int n_ = 0; n_ < 3; ++n_) {
#pragma unroll
        for (int ks_ = 0; ks_ < 2; ++ks_)
          acc[m_][n_] = __builtin_amdgcn_mfma_f32_16x16x32_bf16(
              aS0[m_][ks_], bB[n_][ks_], acc[m_][n_], 0, 0, 0);
#pragma unroll
        for (int ks_ = 0; ks_ < 2; ++ks_)
          acc[4 + m_][n_] = __builtin_amdgcn_mfma_f32_16x16x32_bf16(
              aS1[m_][ks_], bB[n_][ks_], acc[4 + m_][n_], 0, 0, 0);
      }
    __builtin_amdgcn_s_setprio(0);
    // --- certify tile t+1 for next iteration
    if (t < 15) {
      if (t + 2 < 16) {
        VMC7;  // own outstanding: t+1's 7 + t+2's 7 -> retire t+1's
      } else {
        VMC0;  // t=14: only t15's 7 outstanding
      }
      BARR;
    }
  }

  // epilogue: C/D layout col = lane&15, row = (lane>>4)*4 + reg  [m89]
  const int cr = l16 * 4;
#pragma unroll
  for (int nf = 0; nf < 3; ++nf) {
    const int col = n0 + wc * 48 + nf * 16 + fr;  // 0..3071
    const int mat = col >> 10;
    const float* bp = (mat == 0) ? bq : (mat == 1) ? bk : bv;
    const float bval = bp[col & 1023];
#pragma unroll
    for (int mf = 0; mf < 8; ++mf) {
      const int row = m0 + wr * 128 + mf * 16 + cr;
#pragma unroll
      for (int r = 0; r < 4; ++r)
        C[(size_t)(row + r) * QKVN + col] = (bf16_t)(acc[mf][nf][r] + bval);
    }
  }
}

// ============== 128x128 GEMM, 8 waves (O-projection, 2 waves/SIMD) ==========
__global__ __launch_bounds__(512) void gemm_o_kernel(
    const bf16_t* __restrict__ Adat, const bf16_t* __restrict__ W,
    const float* __restrict__ bias, float* __restrict__ out) {
  constexpr int Kd = 1024, Nd = 1024, BK = 32, NT = Kd / BK;
  __shared__ bf16_t ldsA[2][128 * BK];
  __shared__ bf16_t ldsB[2][128 * BK];

  const int m0 = blockIdx.x * 128;
  const int n0 = blockIdx.y * 128;

  const int tid = threadIdx.x;
  const int lane = tid & 63;
  const int wid = tid >> 6;
  const int wr = wid >> 2;  // 0..1 (64 rows each)
  const int wc = wid & 3;   // 0..3 (32 cols each)
  const int fr = lane & 15;
  const int ko = (lane >> 4) * 8;

  f32x4 acc[4][2] = {};

  auto stage = [&](int buf, int t) {
    const int k0 = t * BK;
    const int row = tid >> 2;       // 0..127
    const int kb = (tid & 3) * 16;  // byte offset in 64B row
    async16((const char*)(Adat + (size_t)(m0 + row) * Kd + k0) + kb,
            (char*)ldsA[buf] + row * 64 + kb);
    async16((const char*)(W + (size_t)(n0 + row) * Kd + k0) + kb,
            (char*)ldsB[buf] + row * 64 + kb);
  };

  auto compute = [&](int buf) {
    bf16x8 af[4], bf[2];
#pragma unroll
    for (int i = 0; i < 4; ++i)
      af[i] = *(const bf16x8*)(ldsA[buf] + (wr * 64 + i * 16 + fr) * BK + ko);
#pragma unroll
    for (int j = 0; j < 2; ++j)
      bf[j] = *(const bf16x8*)(ldsB[buf] + (wc * 32 + j * 16 + fr) * BK + ko);
#pragma unroll
    for (int i = 0; i < 4; ++i)
#pragma unroll
      for (int j = 0; j < 2; ++j)
        acc[i][j] = __builtin_amdgcn_mfma_f32_16x16x32_bf16(af[i], bf[j],
                                                            acc[i][j], 0, 0, 0);
  };

  stage(0, 0);
  __syncthreads();
#pragma unroll 1
  for (int t = 0; t < NT; ++t) {
    if (t + 1 < NT) stage((t + 1) & 1, t + 1);
    compute(t & 1);
    __syncthreads();
  }

  const int cr = (lane >> 4) * 4;
#pragma unroll
  for (int j = 0; j < 2; ++j) {
    const int col = n0 + wc * 32 + j * 16 + fr;
    const float bval = bias[col];
#pragma unroll
    for (int i = 0; i < 4; ++i) {
#pragma unroll
      for (int r = 0; r < 4; ++r) {
        const int row = m0 + wr * 64 + i * 16 + cr + r;
        out[(size_t)row * Nd + col] = acc[i][j][r] + bval;
      }
    }
  }
}

// ---------------- local attention (thread-per-query, fused QKV in) ---------
#define CHUNK 256
#define TROWS 260

__global__ __launch_bounds__(256) void attn_kernel(
    const bf16_t* __restrict__ QKV, bf16_t* __restrict__ ctx) {
  __shared__ bf16_t ldsK[TROWS * HDIM];
  __shared__ bf16_t ldsV[TROWS * HDIM];

  const int tid = threadIdx.x;
  const int blk = blockIdx.x;
  const int chunk = blk & 7;
  const int bh = blk >> 3;
  const int h = bh & (NHEADS - 1);
  const int b = bh >> 4;
  const int s0 = chunk * CHUNK;

  const bf16_t* Kb = QKV + (size_t)b * S_LEN * QKVN + DMODEL + h * HDIM;
  const bf16_t* Vb = QKV + (size_t)b * S_LEN * QKVN + 2 * DMODEL + h * HDIM;

#pragma unroll
  for (int j = 0; j < 9; ++j) {
    const int i = j * 256 + tid;
    if (i < TROWS * 8) {
      const int tr = i >> 3;
      const int slot = i & 7;
      const int c = slot ^ (tr & 7);
      int gs = s0 - 2 + tr;
      gs = (gs < 0) ? 0 : (gs >= S_LEN ? S_LEN - 1 : gs);
      async16((const char*)(Kb + (size_t)gs * QKVN) + c * 16,
              (char*)ldsK + i * 16);
      async16((const char*)(Vb + (size_t)gs * QKVN) + c * 16,
              (char*)ldsV + i * 16);
    }
  }

  const int s = s0 + tid;
  const bf16_t* Qrow = QKV + ((size_t)(b * S_LEN) + s) * QKVN + h * HDIM;
  bf16x8 q8[8];
#pragma unroll
  for (int c = 0; c < 8; ++c) q8[c] = *(const bf16x8*)(Qrow + c * 8);
  float qf[64];
#pragma unroll
  for (int c = 0; c < 8; ++c)
#pragma unroll
    for (int e = 0; e < 8; ++e) qf[c * 8 + e] = (float)q8[c][e];

  __syncthreads();

  float sc[5];
#pragma unroll
  for (int jj = 0; jj < 5; ++jj) {
    const int tr = tid + jj;
    float d = 0.f;
#pragma unroll
    for (int c = 0; c < 8; ++c) {
      const bf16x8 k8 = *(const bf16x8*)(ldsK + tr * HDIM + (c ^ (tr & 7)) * 8);
#pragma unroll
      for (int e = 0; e < 8; ++e) d += qf[c * 8 + e] * (float)k8[e];
    }
    const int j = s - 2 + jj;
    sc[jj] = (j < 0 || j >= S_LEN) ? -1e30f : d * 0.125f;
  }

  float m = sc[0];
#pragma unroll
  for (int jj = 1; jj < 5; ++jj) m = fmaxf(m, sc[jj]);
  float p[5], l = 0.f;
#pragma unroll
  for (int jj = 0; jj < 5; ++jj) {
    p[jj] = __expf(sc[jj] - m);
    l += p[jj];
  }
  const float inv = 1.0f / l;
#pragma unroll
  for (int jj = 0; jj < 5; ++jj) p[jj] *= inv;

  float o[64];
#pragma unroll
  for (int e = 0; e < 64; ++e) o[e] = 0.f;
#pragma unroll
  for (int jj = 0; jj < 5; ++jj) {
    const int tr = tid + jj;
    const float pj = p[jj];
#pragma unroll
    for (int c = 0; c < 8; ++c) {
      const bf16x8 v8 = *(const bf16x8*)(ldsV + tr * HDIM + (c ^ (tr & 7)) * 8);
#pragma unroll
      for (int e = 0; e < 8; ++e) o[c * 8 + e] += pj * (float)v8[e];
    }
  }

  bf16_t* Crow = (bf16_t*)ctx + ((size_t)(b * S_LEN) + s) * DMODEL + h * HDIM;
#pragma unroll
  for (int c = 0; c < 8; ++c) {
    bf16x8 ov;
#pragma unroll
    for (int e = 0; e < 8; ++e) ov[e] = (bf16_t)o[c * 8 + e];
    *(bf16x8*)(Crow + c * 8) = ov;
  }
}

extern "C" void kernel_launch(void* const* d_in, const int* in_sizes, int n_in,
                              void* d_out, int out_size, void* d_ws,
                              size_t ws_size, hipStream_t stream) {
  const float* x = (const float*)d_in[0];
  const float* Wq = (const float*)d_in[1];
  const float* bq = (const float*)d_in[2];
  const float* Wk = (const float*)d_in[3];
  const float* bk = (const float*)d_in[4];
  const float* Wv = (const float*)d_in[5];
  const float* bv = (const float*)d_in[6];
  const float* Wo = (const float*)d_in[7];
  const float* bo = (const float*)d_in[8];
  float* out = (float*)d_out;

  const size_t mat = (size_t)BROWS * DMODEL;
  const size_t wmat = (size_t)DMODEL * DMODEL;
  bf16_t* xb = (bf16_t*)d_ws;   // [xb | Wqkv | Wob] contiguous (cvt dst)
  bf16_t* Wqkv = xb + mat;      // fused [3072][1024]
  bf16_t* Wob = Wqkv + 3 * wmat;
  bf16_t* QKV = Wob + wmat;     // fused [4096][3072]
  bf16_t* ctx = QKV + 3 * mat;

  cvt_all_kernel<<<8192, 256, 0, stream>>>(x, Wq, Wk, Wv, Wo, xb);
  gemm_qkv256_kernel<<<dim3(16, 16), 512, 0, stream>>>(xb, Wqkv, bq, bk, bv,
                                                       QKV);
  attn_kernel<<<256, 256, 0, stream>>>(QKV, ctx);
  gemm_o_kernel<<<dim3(32, 8), 512, 0, stream>>>(ctx, Wob, bo, out);
}